// Round 8
// baseline (2865.523 us; speedup 1.0000x reference)
//
#include <hip/hip_runtime.h>
#include <hip/hip_bf16.h>

// Glm4MoeExpertLayers: x[T,H] fp32, Wgu[E,2I,H] fp32, Wdn[E,H,I] fp32, expert_idx
//   gu = x @ Wgu[e]^T ; hidden = silu(gu[:, :I]) * gu[:, I:] ; out = hidden @ Wdn[e]^T
// T=16384 H=2048 I=1536.
// R8: occupancy attack. 256x256-class tiles, BK=32, ring shrunk to 2 buffers
// (64 KiB LDS -> 2 blocks/CU, 16 waves/CU) so cross-block TLP overlaps LDS and
// MFMA pipes (the R3-GEMM2 mechanism). Counted vmcnt(4) kept; lockstep phase
// splitting dropped. Epilogue exchange XOR-swizzled (kills the 2e7 conflict).

namespace {

constexpr int T_ = 16384;
constexpr int H_ = 2048;
constexpr int I_ = 1536;

typedef short short8 __attribute__((ext_vector_type(8)));
typedef float f32x4 __attribute__((ext_vector_type(4)));
typedef unsigned short ushort4v __attribute__((ext_vector_type(4)));

__device__ __forceinline__ unsigned short f2bf(float f) {
    union { float f; unsigned u; } v; v.f = f;
    return (unsigned short)((v.u + 0x7FFFu + ((v.u >> 16) & 1u)) >> 16);
}
__device__ __forceinline__ float bf2f(unsigned short u) {
    union { unsigned u; float f; } v; v.u = (unsigned)u << 16;
    return v.f;
}

typedef __attribute__((address_space(1))) const void gvoid;
typedef __attribute__((address_space(3))) void lvoid;
__device__ __forceinline__ void gload16(const void* g, void* l) {
    __builtin_amdgcn_global_load_lds((gvoid*)g, (lvoid*)l, 16, 0, 0);
}

#define SBAR() do { __builtin_amdgcn_s_barrier(); __builtin_amdgcn_sched_barrier(0); } while (0)
#define VMCNT4() do { asm volatile("s_waitcnt vmcnt(4)" ::: "memory"); __builtin_amdgcn_sched_barrier(0); } while (0)
#define VMCNT0() do { asm volatile("s_waitcnt vmcnt(0)" ::: "memory"); __builtin_amdgcn_sched_barrier(0); } while (0)

// ---------------------------------------------------------------------------
__global__ void k_cvt(const float* __restrict__ base, const int* __restrict__ eidx,
                      long sliceElems, unsigned short* __restrict__ dst, int n4) {
    const float* src = base + (size_t)(*eidx) * (size_t)sliceElems;
    int i = blockIdx.x * blockDim.x + threadIdx.x;
    const int stride = gridDim.x * blockDim.x;
    for (; i < n4; i += stride) {
        f32x4 v = ((const f32x4*)src)[i];
        ushort4v h = { f2bf(v[0]), f2bf(v[1]), f2bf(v[2]), f2bf(v[3]) };
        ((ushort4v*)dst)[i] = h;
    }
}

// ---------------------------------------------------------------------------
// GEMM1 + SwiGLU. 512 thr (8 waves 2Mx4N), M-tile 256, B-rows 256 (gate|up),
// out 256x128 hidden cols. K over H, BK=32, NT=64. 2-buffer double-buffer.
// ---------------------------------------------------------------------------
__global__ __launch_bounds__(512, 4) void k_gemm1_swiglu(
    const unsigned short* __restrict__ xb, const unsigned short* __restrict__ wgub,
    unsigned short* __restrict__ hidden)
{
    // 2 buffers: each A[256][32] + B[256][32] bf16 = 32 KiB. Total 64 KiB.
    __shared__ unsigned short lds[2 * 16384];

    const int tid  = threadIdx.x;
    const int lane = tid & 63;
    const int wid  = tid >> 6;
    const int wr   = wid >> 2;     // 0..1  M half
    const int wc   = wid & 3;      // 0..3  B quarter (0,1=gate 2,3=up)
    const int l15  = lane & 15;
    const int l4   = lane >> 4;

    const int nb = (blockIdx.x & 7) * 96 + (blockIdx.x >> 3);
    const int bx = nb % 12, by = nb / 12;
    const int m0 = by * 256;
    const int n0 = bx * 128;

    const int srow = lane >> 2;
    const int scol = (lane & 3) * 8;

    f32x4 acc[8][4];
    #pragma unroll
    for (int m = 0; m < 8; ++m)
        #pragma unroll
        for (int n = 0; n < 4; ++n) acc[m][n] = (f32x4)0.0f;

    constexpr int NT = H_ / 32;   // 64

    const int aoff = wr * 4096 + l15 * 32 + l4 * 8;
    const int boff = wc * 2048 + l15 * 32 + l4 * 8;

    auto stage = [&](int s) {
        unsigned short* stA = lds + (s & 1) * 16384;
        unsigned short* stB = stA + 8192;
        const int kS = s * 32;
        #pragma unroll
        for (int j = 0; j < 2; ++j) {
            const int rb = (wid * 2 + j) * 16;
            gload16(xb + (size_t)(m0 + rb + srow) * H_ + kS + scol, stA + rb * 32);
        }
        #pragma unroll
        for (int j = 0; j < 2; ++j) {
            const int rb = (wid * 2 + j) * 16;
            const int growb = (rb < 128) ? (n0 + rb) : (I_ + n0 + rb - 128);
            gload16(wgub + (size_t)(growb + srow) * H_ + kS + scol, stB + rb * 32);
        }
    };

    stage(0);

    for (int t = 0; t < NT; ++t) {
        if (t + 1 < NT) { stage(t + 1); VMCNT4(); }
        else            { VMCNT0(); }
        SBAR();

        const unsigned short* bA = lds + (t & 1) * 16384;
        const unsigned short* bB = bA + 8192;
        short8 af[8], bf[4];
        #pragma unroll
        for (int a = 0; a < 8; ++a) af[a] = *(const short8*)(bA + aoff + a * 512);
        #pragma unroll
        for (int n = 0; n < 4; ++n) bf[n] = *(const short8*)(bB + boff + n * 512);
        __builtin_amdgcn_s_setprio(1);
        #pragma unroll
        for (int a = 0; a < 8; ++a)
            #pragma unroll
            for (int n = 0; n < 4; ++n)
                acc[a][n] = __builtin_amdgcn_mfma_f32_16x16x32_bf16(af[a], bf[n], acc[a][n], 0, 0, 0);
        __builtin_amdgcn_s_setprio(0);
        SBAR();   // all waves done reading buf[t&1] before next stage overwrites it
    }

    // ---- SwiGLU cross-wave epilogue, XOR-swizzled bf16 exchange (64 KiB)
    unsigned short* exch = lds;   // [256][128] bf16, col ^ (((row>>2)&3)<<2)
    if (wc >= 2) {
        #pragma unroll
        for (int m = 0; m < 8; ++m)
            #pragma unroll
            for (int n = 0; n < 4; ++n)
                #pragma unroll
                for (int j = 0; j < 4; ++j) {
                    const int row = wr * 128 + m * 16 + l4 * 4 + j;
                    const int col = (wc - 2) * 64 + n * 16 + l15;
                    exch[row * 128 + (col ^ (((row >> 2) & 3) << 2))] = f2bf(acc[m][n][j]);
                }
    }
    __syncthreads();
    if (wc < 2) {
        #pragma unroll
        for (int m = 0; m < 8; ++m)
            #pragma unroll
            for (int n = 0; n < 4; ++n)
                #pragma unroll
                for (int j = 0; j < 4; ++j) {
                    const int row = wr * 128 + m * 16 + l4 * 4 + j;
                    const int col = wc * 64 + n * 16 + l15;
                    const float g = acc[m][n][j];
                    const float u = bf2f(exch[row * 128 + (col ^ (((row >> 2) & 3) << 2))]);
                    const float s = g / (1.0f + __expf(-g));
                    hidden[(size_t)(m0 + row) * I_ + n0 + col] = f2bf(s * u);
                }
    }
}

// ---------------------------------------------------------------------------
// GEMM2: out[T,H] fp32 = hidden(bf16) @ wdn_bf16^T. 256x256 tile, NT=48.
// ---------------------------------------------------------------------------
__global__ __launch_bounds__(512, 4) void k_gemm2(
    const unsigned short* __restrict__ hidden, const unsigned short* __restrict__ wdnb,
    float* __restrict__ out)
{
    __shared__ unsigned short lds[2 * 16384];

    const int tid  = threadIdx.x;
    const int lane = tid & 63;
    const int wid  = tid >> 6;
    const int wr   = wid >> 2;
    const int wc   = wid & 3;
    const int l15  = lane & 15;
    const int l4   = lane >> 4;

    const int nb = (blockIdx.x & 7) * 64 + (blockIdx.x >> 3);
    const int bx = nb & 7, by = nb >> 3;
    const int m0 = by * 256;
    const int n0 = bx * 256;

    const int srow = lane >> 2;
    const int scol = (lane & 3) * 8;

    f32x4 acc[8][4];
    #pragma unroll
    for (int m = 0; m < 8; ++m)
        #pragma unroll
        for (int n = 0; n < 4; ++n) acc[m][n] = (f32x4)0.0f;

    constexpr int NT = I_ / 32;   // 48

    const int aoff = wr * 4096 + l15 * 32 + l4 * 8;
    const int boff = wc * 2048 + l15 * 32 + l4 * 8;

    auto stage = [&](int s) {
        unsigned short* stA = lds + (s & 1) * 16384;
        unsigned short* stB = stA + 8192;
        const int kS = s * 32;
        #pragma unroll
        for (int j = 0; j < 2; ++j) {
            const int rb = (wid * 2 + j) * 16;
            gload16(hidden + (size_t)(m0 + rb + srow) * I_ + kS + scol, stA + rb * 32);
        }
        #pragma unroll
        for (int j = 0; j < 2; ++j) {
            const int rb = (wid * 2 + j) * 16;
            gload16(wdnb + (size_t)(n0 + rb + srow) * I_ + kS + scol, stB + rb * 32);
        }
    };

    stage(0);

    for (int t = 0; t < NT; ++t) {
        if (t + 1 < NT) { stage(t + 1); VMCNT4(); }
        else            { VMCNT0(); }
        SBAR();

        const unsigned short* bA = lds + (t & 1) * 16384;
        const unsigned short* bB = bA + 8192;
        short8 af[8], bf[4];
        #pragma unroll
        for (int a = 0; a < 8; ++a) af[a] = *(const short8*)(bA + aoff + a * 512);
        #pragma unroll
        for (int n = 0; n < 4; ++n) bf[n] = *(const short8*)(bB + boff + n * 512);
        __builtin_amdgcn_s_setprio(1);
        #pragma unroll
        for (int a = 0; a < 8; ++a)
            #pragma unroll
            for (int n = 0; n < 4; ++n)
                acc[a][n] = __builtin_amdgcn_mfma_f32_16x16x32_bf16(af[a], bf[n], acc[a][n], 0, 0, 0);
        __builtin_amdgcn_s_setprio(0);
        SBAR();
    }

    #pragma unroll
    for (int m = 0; m < 8; ++m)
        #pragma unroll
        for (int n = 0; n < 4; ++n)
            #pragma unroll
            for (int j = 0; j < 4; ++j) {
                const int row = m0 + wr * 128 + m * 16 + l4 * 4 + j;
                const int col = n0 + wc * 64 + n * 16 + l15;
                out[(size_t)row * H_ + col] = acc[m][n][j];
            }
}

} // namespace

extern "C" void kernel_launch(void* const* d_in, const int* in_sizes, int n_in,
                              void* d_out, int out_size, void* d_ws, size_t ws_size,
                              hipStream_t stream) {
    const float* x   = (const float*)d_in[0];   // [T, H]
    const float* wgu = (const float*)d_in[1];   // [E, 2I, H]
    const float* wdn = (const float*)d_in[2];   // [E, H, I]
    const int* eidx  = (const int*)d_in[3];     // [1]
    float* out = (float*)d_out;                 // [T, H]

    // d_out (134.2 MB fp32) temporarily holds xb (67.1 MB) — dead before k_gemm2
    // overwrites it. ws: hidden | wgu_bf16 | wdn_bf16 = 69.2 MB.
    unsigned short* xb     = (unsigned short*)d_out;
    unsigned short* hidden = (unsigned short*)d_ws;
    unsigned short* wgub   = (unsigned short*)((char*)d_ws + 50331648);
    unsigned short* wdnb   = (unsigned short*)((char*)d_ws + 62914560);

    k_cvt<<<2048, 256, 0, stream>>>(x, eidx, 0L, xb, (T_ * H_) / 4);
    k_cvt<<<2048, 256, 0, stream>>>(wgu, eidx, (long)(2 * I_) * H_, wgub, (2 * I_ * H_) / 4);
    k_cvt<<<2048, 256, 0, stream>>>(wdn, eidx, (long)H_ * I_, wdnb, (H_ * I_) / 4);
    k_gemm1_swiglu<<<dim3((T_ / 256) * (I_ / 128)), 512, 0, stream>>>(xb, wgub, hidden);
    k_gemm2<<<dim3((T_ / 256) * (H_ / 256)), 512, 0, stream>>>(hidden, wdnb, out);
}

// Round 9
// 355.544 us; speedup vs baseline: 8.0596x; 8.0596x over previous
//
#include <hip/hip_runtime.h>
#include <hip/hip_bf16.h>

// Glm4MoeExpertLayers: x[T,H] fp32, Wgu[E,2I,H] fp32, Wdn[E,H,I] fp32, expert_idx
//   gu = x @ Wgu[e]^T ; hidden = silu(gu[:, :I]) * gu[:, I:] ; out = hidden @ Wdn[e]^T
// T=16384 H=2048 I=1536.
// R9: bank-conflict-free BK=64 (128B rows, 8 x 16B slots, slot ^= row&7 swizzle
// via pre-swizzled global source + swizzled read; gload_lds dest stays linear).
// Ring-2 (128 KiB), 4 JIT phases/K-tile {read frags, setprio MFMA16, barrier},
// stage t+1 at body top, vmcnt(0) only at body end (issue->wait ~2000cyc).
// R8 lesson: launch_bounds min-waves=4 capped VGPR at 128 < acc(128) -> spill
// disaster (VGPR_Count 64, 8GB scratch traffic). Keep (512,2).

namespace {

constexpr int T_ = 16384;
constexpr int H_ = 2048;
constexpr int I_ = 1536;

typedef short short8 __attribute__((ext_vector_type(8)));
typedef float f32x4 __attribute__((ext_vector_type(4)));
typedef unsigned short ushort4v __attribute__((ext_vector_type(4)));

__device__ __forceinline__ unsigned short f2bf(float f) {
    union { float f; unsigned u; } v; v.f = f;
    return (unsigned short)((v.u + 0x7FFFu + ((v.u >> 16) & 1u)) >> 16);
}
__device__ __forceinline__ float bf2f(unsigned short u) {
    union { unsigned u; float f; } v; v.u = (unsigned)u << 16;
    return v.f;
}

typedef __attribute__((address_space(1))) const void gvoid;
typedef __attribute__((address_space(3))) void lvoid;
__device__ __forceinline__ void gload16(const void* g, void* l) {
    __builtin_amdgcn_global_load_lds((gvoid*)g, (lvoid*)l, 16, 0, 0);
}

#define SBAR() do { __builtin_amdgcn_s_barrier(); __builtin_amdgcn_sched_barrier(0); } while (0)
#define VMCNT0() do { asm volatile("s_waitcnt vmcnt(0)" ::: "memory"); __builtin_amdgcn_sched_barrier(0); } while (0)

// ---------------------------------------------------------------------------
__global__ void k_cvt(const float* __restrict__ base, const int* __restrict__ eidx,
                      long sliceElems, unsigned short* __restrict__ dst, int n4) {
    const float* src = base + (size_t)(*eidx) * (size_t)sliceElems;
    int i = blockIdx.x * blockDim.x + threadIdx.x;
    const int stride = gridDim.x * blockDim.x;
    for (; i < n4; i += stride) {
        f32x4 v = ((const f32x4*)src)[i];
        ushort4v h = { f2bf(v[0]), f2bf(v[1]), f2bf(v[2]), f2bf(v[3]) };
        ((ushort4v*)dst)[i] = h;
    }
}

// ---------------------------------------------------------------------------
// GEMM1 + SwiGLU. 512 thr (8 waves 2Mx4N), M-tile 256, B-rows 256 (gate|up),
// out 256x128 hidden cols. K over H, BK=64, NT=32. Ring-2 LDS (128 KiB).
// LDS tile layout: [256 rows][8 slots of 16B], physical slot = logical ^ (row&7).
// ---------------------------------------------------------------------------
__global__ __launch_bounds__(512, 2) void k_gemm1_swiglu(
    const unsigned short* __restrict__ xb, const unsigned short* __restrict__ wgub,
    unsigned short* __restrict__ hidden)
{
    __shared__ unsigned short lds[2 * 32768];   // buf: A[256][64] + B[256][64] ushorts

    const int tid  = threadIdx.x;
    const int lane = tid & 63;
    const int wid  = tid >> 6;
    const int wr   = wid >> 2;     // 0..1 M half
    const int wc   = wid & 3;      // 0..3 B quarter (0,1=gate 2,3=up)
    const int l15  = lane & 15;
    const int l4   = lane >> 4;    // 0..3
    const int sw   = l15 & 7;      // read-swizzle key (row&7 == l15&7 for 16-aligned frags)

    const int nb = (blockIdx.x & 7) * 96 + (blockIdx.x >> 3);
    const int bx = nb % 12, by = nb / 12;
    const int m0 = by * 256;
    const int n0 = bx * 128;

    const int srow8 = lane >> 3;   // 0..7 staging row within 8-row wave chunk
    const int sslot = lane & 7;    // physical slot this lane's 16B lands in

    f32x4 acc[8][4];
    #pragma unroll
    for (int m = 0; m < 8; ++m)
        #pragma unroll
        for (int n = 0; n < 4; ++n) acc[m][n] = (f32x4)0.0f;

    constexpr int NT = H_ / 64;   // 32

    auto stage = [&](int s) {
        unsigned short* dA = lds + (s & 1) * 32768;
        unsigned short* dB = dA + 16384;
        const int kS = s * 64;
        #pragma unroll
        for (int g = 0; g < 4; ++g) {
            const int row  = g * 64 + wid * 8 + srow8;
            const int gcol = ((sslot ^ (row & 7)) * 8);       // pre-swizzled source col
            const int dof  = g * 4096 + wid * 512;            // linear dest (ushorts)
            gload16(xb + (size_t)(m0 + row) * H_ + kS + gcol, dA + dof);
            const int grow = (row < 128) ? (n0 + row) : (I_ + n0 + row - 128);
            gload16(wgub + (size_t)grow * H_ + kS + gcol, dB + dof);
        }
    };
    // frag reads: row = base + l15, logical slot kk*4+l4, physical = ^(row&7)=^sw
    auto readA = [&](int buf, int mh, int kk, short8 (&F)[4]) {
        const unsigned short* bA = lds + buf * 32768;
        const int sl = ((kk * 4 + l4) ^ sw) * 8;
        #pragma unroll
        for (int m = 0; m < 4; ++m) {
            const int row = wr * 128 + (mh * 4 + m) * 16 + l15;
            F[m] = *(const short8*)(bA + row * 64 + sl);
        }
    };
    auto readB = [&](int buf, int kk, short8 (&F)[4]) {
        const unsigned short* bB = lds + buf * 32768 + 16384;
        const int sl = ((kk * 4 + l4) ^ sw) * 8;
        #pragma unroll
        for (int n = 0; n < 4; ++n) {
            const int row = wc * 64 + n * 16 + l15;
            F[n] = *(const short8*)(bB + row * 64 + sl);
        }
    };

    stage(0);
    VMCNT0();
    SBAR();

    short8 af[4], bf[4];
    for (int t = 0; t < NT; ++t) {
        const int buf = t & 1;
        if (t + 1 < NT) stage(t + 1);

        // ph0: kk0, m-half 0 (+B kk0)
        readA(buf, 0, 0, af); readB(buf, 0, bf);
        __builtin_amdgcn_s_setprio(1);
        #pragma unroll
        for (int a = 0; a < 4; ++a)
            #pragma unroll
            for (int n = 0; n < 4; ++n)
                acc[a][n] = __builtin_amdgcn_mfma_f32_16x16x32_bf16(af[a], bf[n], acc[a][n], 0, 0, 0);
        __builtin_amdgcn_s_setprio(0);
        SBAR();
        // ph1: kk0, m-half 1
        readA(buf, 1, 0, af);
        __builtin_amdgcn_s_setprio(1);
        #pragma unroll
        for (int a = 0; a < 4; ++a)
            #pragma unroll
            for (int n = 0; n < 4; ++n)
                acc[4 + a][n] = __builtin_amdgcn_mfma_f32_16x16x32_bf16(af[a], bf[n], acc[4 + a][n], 0, 0, 0);
        __builtin_amdgcn_s_setprio(0);
        SBAR();
        // ph2: kk1, m-half 0 (+B kk1)
        readA(buf, 0, 1, af); readB(buf, 1, bf);
        __builtin_amdgcn_s_setprio(1);
        #pragma unroll
        for (int a = 0; a < 4; ++a)
            #pragma unroll
            for (int n = 0; n < 4; ++n)
                acc[a][n] = __builtin_amdgcn_mfma_f32_16x16x32_bf16(af[a], bf[n], acc[a][n], 0, 0, 0);
        __builtin_amdgcn_s_setprio(0);
        SBAR();
        // ph3: kk1, m-half 1; then buffer guard
        readA(buf, 1, 1, af);
        __builtin_amdgcn_s_setprio(1);
        #pragma unroll
        for (int a = 0; a < 4; ++a)
            #pragma unroll
            for (int n = 0; n < 4; ++n)
                acc[4 + a][n] = __builtin_amdgcn_mfma_f32_16x16x32_bf16(af[a], bf[n], acc[4 + a][n], 0, 0, 0);
        __builtin_amdgcn_s_setprio(0);
        if (t + 1 < NT) { VMCNT0(); }   // t+1's 8 gloads issued ~4 phases ago
        SBAR();
    }

    // ---- SwiGLU cross-wave epilogue, XOR-swizzled bf16 exchange
    __syncthreads();
    unsigned short* exch = lds;   // [256][128] bf16
    if (wc >= 2) {
        #pragma unroll
        for (int m = 0; m < 8; ++m)
            #pragma unroll
            for (int n = 0; n < 4; ++n)
                #pragma unroll
                for (int j = 0; j < 4; ++j) {
                    const int row = wr * 128 + m * 16 + l4 * 4 + j;
                    const int col = (wc - 2) * 64 + n * 16 + l15;
                    exch[row * 128 + (col ^ (((row >> 2) & 3) << 2))] = f2bf(acc[m][n][j]);
                }
    }
    __syncthreads();
    if (wc < 2) {
        #pragma unroll
        for (int m = 0; m < 8; ++m)
            #pragma unroll
            for (int n = 0; n < 4; ++n)
                #pragma unroll
                for (int j = 0; j < 4; ++j) {
                    const int row = wr * 128 + m * 16 + l4 * 4 + j;
                    const int col = wc * 64 + n * 16 + l15;
                    const float g = acc[m][n][j];
                    const float u = bf2f(exch[row * 128 + (col ^ (((row >> 2) & 3) << 2))]);
                    const float s = g / (1.0f + __expf(-g));
                    hidden[(size_t)(m0 + row) * I_ + n0 + col] = f2bf(s * u);
                }
    }
}

// ---------------------------------------------------------------------------
// GEMM2: out[T,H] fp32 = hidden(bf16) @ wdn_bf16^T. Same pipeline, NT=24,
// 256x256 output tile.
// ---------------------------------------------------------------------------
__global__ __launch_bounds__(512, 2) void k_gemm2(
    const unsigned short* __restrict__ hidden, const unsigned short* __restrict__ wdnb,
    float* __restrict__ out)
{
    __shared__ unsigned short lds[2 * 32768];

    const int tid  = threadIdx.x;
    const int lane = tid & 63;
    const int wid  = tid >> 6;
    const int wr   = wid >> 2;
    const int wc   = wid & 3;
    const int l15  = lane & 15;
    const int l4   = lane >> 4;
    const int sw   = l15 & 7;

    const int nb = (blockIdx.x & 7) * 64 + (blockIdx.x >> 3);
    const int bx = nb & 7, by = nb >> 3;
    const int m0 = by * 256;
    const int n0 = bx * 256;

    const int srow8 = lane >> 3;
    const int sslot = lane & 7;

    f32x4 acc[8][4];
    #pragma unroll
    for (int m = 0; m < 8; ++m)
        #pragma unroll
        for (int n = 0; n < 4; ++n) acc[m][n] = (f32x4)0.0f;

    constexpr int NT = I_ / 64;   // 24

    auto stage = [&](int s) {
        unsigned short* dA = lds + (s & 1) * 32768;
        unsigned short* dB = dA + 16384;
        const int kS = s * 64;
        #pragma unroll
        for (int g = 0; g < 4; ++g) {
            const int row  = g * 64 + wid * 8 + srow8;
            const int gcol = ((sslot ^ (row & 7)) * 8);
            const int dof  = g * 4096 + wid * 512;
            gload16(hidden + (size_t)(m0 + row) * I_ + kS + gcol, dA + dof);
            gload16(wdnb   + (size_t)(n0 + row) * I_ + kS + gcol, dB + dof);
        }
    };
    auto readA = [&](int buf, int mh, int kk, short8 (&F)[4]) {
        const unsigned short* bA = lds + buf * 32768;
        const int sl = ((kk * 4 + l4) ^ sw) * 8;
        #pragma unroll
        for (int m = 0; m < 4; ++m) {
            const int row = wr * 128 + (mh * 4 + m) * 16 + l15;
            F[m] = *(const short8*)(bA + row * 64 + sl);
        }
    };
    auto readB = [&](int buf, int kk, short8 (&F)[4]) {
        const unsigned short* bB = lds + buf * 32768 + 16384;
        const int sl = ((kk * 4 + l4) ^ sw) * 8;
        #pragma unroll
        for (int n = 0; n < 4; ++n) {
            const int row = wc * 64 + n * 16 + l15;
            F[n] = *(const short8*)(bB + row * 64 + sl);
        }
    };

    stage(0);
    VMCNT0();
    SBAR();

    short8 af[4], bf[4];
    for (int t = 0; t < NT; ++t) {
        const int buf = t & 1;
        if (t + 1 < NT) stage(t + 1);

        readA(buf, 0, 0, af); readB(buf, 0, bf);
        __builtin_amdgcn_s_setprio(1);
        #pragma unroll
        for (int a = 0; a < 4; ++a)
            #pragma unroll
            for (int n = 0; n < 4; ++n)
                acc[a][n] = __builtin_amdgcn_mfma_f32_16x16x32_bf16(af[a], bf[n], acc[a][n], 0, 0, 0);
        __builtin_amdgcn_s_setprio(0);
        SBAR();
        readA(buf, 1, 0, af);
        __builtin_amdgcn_s_setprio(1);
        #pragma unroll
        for (int a = 0; a < 4; ++a)
            #pragma unroll
            for (int n = 0; n < 4; ++n)
                acc[4 + a][n] = __builtin_amdgcn_mfma_f32_16x16x32_bf16(af[a], bf[n], acc[4 + a][n], 0, 0, 0);
        __builtin_amdgcn_s_setprio(0);
        SBAR();
        readA(buf, 0, 1, af); readB(buf, 1, bf);
        __builtin_amdgcn_s_setprio(1);
        #pragma unroll
        for (int a = 0; a < 4; ++a)
            #pragma unroll
            for (int n = 0; n < 4; ++n)
                acc[a][n] = __builtin_amdgcn_mfma_f32_16x16x32_bf16(af[a], bf[n], acc[a][n], 0, 0, 0);
        __builtin_amdgcn_s_setprio(0);
        SBAR();
        readA(buf, 1, 1, af);
        __builtin_amdgcn_s_setprio(1);
        #pragma unroll
        for (int a = 0; a < 4; ++a)
            #pragma unroll
            for (int n = 0; n < 4; ++n)
                acc[4 + a][n] = __builtin_amdgcn_mfma_f32_16x16x32_bf16(af[a], bf[n], acc[4 + a][n], 0, 0, 0);
        __builtin_amdgcn_s_setprio(0);
        if (t + 1 < NT) { VMCNT0(); }
        SBAR();
    }

    #pragma unroll
    for (int m = 0; m < 8; ++m)
        #pragma unroll
        for (int n = 0; n < 4; ++n)
            #pragma unroll
            for (int j = 0; j < 4; ++j) {
                const int row = m0 + wr * 128 + m * 16 + l4 * 4 + j;
                const int col = n0 + wc * 64 + n * 16 + l15;
                out[(size_t)row * H_ + col] = acc[m][n][j];
            }
}

} // namespace

extern "C" void kernel_launch(void* const* d_in, const int* in_sizes, int n_in,
                              void* d_out, int out_size, void* d_ws, size_t ws_size,
                              hipStream_t stream) {
    const float* x   = (const float*)d_in[0];   // [T, H]
    const float* wgu = (const float*)d_in[1];   // [E, 2I, H]
    const float* wdn = (const float*)d_in[2];   // [E, H, I]
    const int* eidx  = (const int*)d_in[3];     // [1]
    float* out = (float*)d_out;                 // [T, H]

    // d_out (134.2 MB fp32) temporarily holds xb (67.1 MB) — dead before k_gemm2
    // overwrites it. ws: hidden | wgu_bf16 | wdn_bf16 = 69.2 MB.
    unsigned short* xb     = (unsigned short*)d_out;
    unsigned short* hidden = (unsigned short*)d_ws;
    unsigned short* wgub   = (unsigned short*)((char*)d_ws + 50331648);
    unsigned short* wdnb   = (unsigned short*)((char*)d_ws + 62914560);

    k_cvt<<<2048, 256, 0, stream>>>(x, eidx, 0L, xb, (T_ * H_) / 4);
    k_cvt<<<2048, 256, 0, stream>>>(wgu, eidx, (long)(2 * I_) * H_, wgub, (2 * I_ * H_) / 4);
    k_cvt<<<2048, 256, 0, stream>>>(wdn, eidx, (long)H_ * I_, wdnb, (H_ * I_) / 4);
    k_gemm1_swiglu<<<dim3((T_ / 256) * (I_ / 128)), 512, 0, stream>>>(xb, wgub, hidden);
    k_gemm2<<<dim3((T_ / 256) * (H_ / 256)), 512, 0, stream>>>(hidden, wdnb, out);
}

// Round 10
// 338.426 us; speedup vs baseline: 8.4672x; 1.0506x over previous
//
#include <hip/hip_runtime.h>
#include <hip/hip_bf16.h>

// Glm4MoeExpertLayers: x[T,H] fp32, Wgu[E,2I,H] fp32, Wdn[E,H,I] fp32, expert_idx
//   gu = x @ Wgu[e]^T ; hidden = silu(gu[:, :I]) * gu[:, I:] ; out = hidden @ Wdn[e]^T
// T=16384 H=2048 I=1536.
// R10 = R3 (128^2 two-barrier gload_lds structure, high TLP: 3-5 blocks/CU,
// free-running waves do LDS<->MFMA overlap) + R9's PROVEN conflict-free swizzle:
//   stage: pre-swizzled global col ((lane&7)^(row&7))*8, linear gload_lds dest
//   read:  physical slot = (kk*4+l4) ^ (l15&7)
// No inline-asm schedule (R4-R9 lockstep phases all null or worse).

namespace {

constexpr int T_ = 16384;
constexpr int H_ = 2048;
constexpr int I_ = 1536;

typedef short short8 __attribute__((ext_vector_type(8)));
typedef float f32x4 __attribute__((ext_vector_type(4)));
typedef unsigned short ushort4v __attribute__((ext_vector_type(4)));

__device__ __forceinline__ unsigned short f2bf(float f) {
    union { float f; unsigned u; } v; v.f = f;
    return (unsigned short)((v.u + 0x7FFFu + ((v.u >> 16) & 1u)) >> 16);
}

typedef __attribute__((address_space(1))) const void gvoid;
typedef __attribute__((address_space(3))) void lvoid;
__device__ __forceinline__ void gload16(const void* g, void* l) {
    __builtin_amdgcn_global_load_lds((gvoid*)g, (lvoid*)l, 16, 0, 0);
}

// ---------------------------------------------------------------------------
__global__ void k_cvt(const float* __restrict__ base, const int* __restrict__ eidx,
                      long sliceElems, unsigned short* __restrict__ dst, int n4) {
    const float* src = base + (size_t)(*eidx) * (size_t)sliceElems;
    int i = blockIdx.x * blockDim.x + threadIdx.x;
    const int stride = gridDim.x * blockDim.x;
    for (; i < n4; i += stride) {
        f32x4 v = ((const f32x4*)src)[i];
        ushort4v h = { f2bf(v[0]), f2bf(v[1]), f2bf(v[2]), f2bf(v[3]) };
        ((ushort4v*)dst)[i] = h;
    }
}

// ---------------------------------------------------------------------------
// GEMM1 + SwiGLU: hidden[T,I](bf16) = silu(xb@Wg^T) * (xb@Wu^T)
// 256 thr (4 waves 2x2), tile 128x128, BK=64 over H. Dual-B in-wave (no
// cross-wave exchange). LDS 3 x [128][64] = 48 KiB -> 3 blocks/CU.
// ---------------------------------------------------------------------------
__global__ __launch_bounds__(256, 2) void k_gemm1_swiglu(
    const unsigned short* __restrict__ xb, const unsigned short* __restrict__ wgub,
    unsigned short* __restrict__ hidden)
{
    __shared__ unsigned short lds[3 * 128 * 64];
    unsigned short* ldsA  = lds;                 // [128 rows][8 slots of 16B], swizzled
    unsigned short* ldsBg = lds + 128 * 64;
    unsigned short* ldsBu = lds + 2 * 128 * 64;

    const int tid  = threadIdx.x;
    const int lane = tid & 63;
    const int wv   = tid >> 6;
    const int wr   = wv >> 1, wc = wv & 1;

    // XCD-aware bijective swizzle over 1536 blocks (1536 % 8 == 0)
    const int nb = (blockIdx.x & 7) * 192 + (blockIdx.x >> 3);
    const int bx = nb % 12, by = nb / 12;
    const int m0 = by * 128;
    const int n0 = bx * 128;

    f32x4 accG[4][4], accU[4][4];
    #pragma unroll
    for (int a = 0; a < 4; ++a)
        #pragma unroll
        for (int b = 0; b < 4; ++b) { accG[a][b] = (f32x4)0.0f; accU[a][b] = (f32x4)0.0f; }

    const int drow = lane >> 3;                       // 0..7 (== row & 7)
    const int gcol = (((lane & 7) ^ drow) * 8);       // pre-swizzled source col (bf16)
    const int l15 = lane & 15;
    const int l4  = lane >> 4;
    const int sw  = l15 & 7;                          // read swizzle key

    for (int k0 = 0; k0 < H_; k0 += 64) {
        __syncthreads();
        #pragma unroll
        for (int r = 0; r < 4; ++r) {
            const int row  = r * 32 + wv * 8 + drow;
            const int loff = r * 2048 + wv * 512;     // ushort units, wave-uniform
            gload16(xb   + (size_t)(m0 + row)      * H_ + k0 + gcol, ldsA  + loff);
            gload16(wgub + (size_t)(n0 + row)      * H_ + k0 + gcol, ldsBg + loff);
            gload16(wgub + (size_t)(I_ + n0 + row) * H_ + k0 + gcol, ldsBu + loff);
        }
        __syncthreads();

        #pragma unroll
        for (int kk = 0; kk < 2; ++kk) {
            const int sl = ((kk * 4 + l4) ^ sw) * 8;  // physical slot byte-chunk (ushorts)
            short8 af[4], bg[4], bu[4];
            #pragma unroll
            for (int a = 0; a < 4; ++a) {
                const int r = wr * 64 + a * 16 + l15;
                af[a] = *(const short8*)(ldsA + r * 64 + sl);
            }
            #pragma unroll
            for (int b = 0; b < 4; ++b) {
                const int r = wc * 64 + b * 16 + l15;
                bg[b] = *(const short8*)(ldsBg + r * 64 + sl);
                bu[b] = *(const short8*)(ldsBu + r * 64 + sl);
            }
            #pragma unroll
            for (int a = 0; a < 4; ++a)
                #pragma unroll
                for (int b = 0; b < 4; ++b) {
                    accG[a][b] = __builtin_amdgcn_mfma_f32_16x16x32_bf16(af[a], bg[b], accG[a][b], 0, 0, 0);
                    accU[a][b] = __builtin_amdgcn_mfma_f32_16x16x32_bf16(af[a], bu[b], accU[a][b], 0, 0, 0);
                }
        }
    }

    // epilogue: silu(gate)*up -> bf16 hidden (in-wave, no LDS exchange)
    #pragma unroll
    for (int a = 0; a < 4; ++a)
        #pragma unroll
        for (int b = 0; b < 4; ++b)
            #pragma unroll
            for (int j = 0; j < 4; ++j) {
                const int row = m0 + wr * 64 + a * 16 + l4 * 4 + j;
                const int col = n0 + wc * 64 + b * 16 + l15;
                const float g = accG[a][b][j];
                const float u = accU[a][b][j];
                const float s = g / (1.0f + __expf(-g));
                hidden[(size_t)row * I_ + col] = f2bf(s * u);
            }
}

// ---------------------------------------------------------------------------
// GEMM2: out[T,H] fp32 = hidden(bf16) @ wdn_bf16^T. 128x128 tile, BK=64 over I.
// LDS 2 x 16 KiB = 32 KiB -> 5 blocks/CU.
// ---------------------------------------------------------------------------
__global__ __launch_bounds__(256, 2) void k_gemm2(
    const unsigned short* __restrict__ hidden, const unsigned short* __restrict__ wdnb,
    float* __restrict__ out)
{
    __shared__ unsigned short lds[2 * 128 * 64];
    unsigned short* ldsA = lds;
    unsigned short* ldsB = lds + 128 * 64;

    const int tid  = threadIdx.x;
    const int lane = tid & 63;
    const int wv   = tid >> 6;
    const int wr   = wv >> 1, wc = wv & 1;

    // XCD swizzle over 2048 blocks (2048 % 8 == 0)
    const int nb = (blockIdx.x & 7) * 256 + (blockIdx.x >> 3);
    const int bx = nb % 16, by = nb / 16;
    const int m0 = by * 128;
    const int n0 = bx * 128;

    f32x4 acc[4][4];
    #pragma unroll
    for (int a = 0; a < 4; ++a)
        #pragma unroll
        for (int b = 0; b < 4; ++b) acc[a][b] = (f32x4)0.0f;

    const int drow = lane >> 3;
    const int gcol = (((lane & 7) ^ drow) * 8);
    const int l15 = lane & 15;
    const int l4  = lane >> 4;
    const int sw  = l15 & 7;

    for (int k0 = 0; k0 < I_; k0 += 64) {
        __syncthreads();
        #pragma unroll
        for (int r = 0; r < 4; ++r) {
            const int row  = r * 32 + wv * 8 + drow;
            const int loff = r * 2048 + wv * 512;
            gload16(hidden + (size_t)(m0 + row) * I_ + k0 + gcol, ldsA + loff);
            gload16(wdnb   + (size_t)(n0 + row) * I_ + k0 + gcol, ldsB + loff);
        }
        __syncthreads();

        #pragma unroll
        for (int kk = 0; kk < 2; ++kk) {
            const int sl = ((kk * 4 + l4) ^ sw) * 8;
            short8 af[4], bw[4];
            #pragma unroll
            for (int a = 0; a < 4; ++a) {
                const int r = wr * 64 + a * 16 + l15;
                af[a] = *(const short8*)(ldsA + r * 64 + sl);
            }
            #pragma unroll
            for (int b = 0; b < 4; ++b) {
                const int r = wc * 64 + b * 16 + l15;
                bw[b] = *(const short8*)(ldsB + r * 64 + sl);
            }
            #pragma unroll
            for (int a = 0; a < 4; ++a)
                #pragma unroll
                for (int b = 0; b < 4; ++b)
                    acc[a][b] = __builtin_amdgcn_mfma_f32_16x16x32_bf16(af[a], bw[b], acc[a][b], 0, 0, 0);
        }
    }

    #pragma unroll
    for (int a = 0; a < 4; ++a)
        #pragma unroll
        for (int b = 0; b < 4; ++b)
            #pragma unroll
            for (int j = 0; j < 4; ++j) {
                const int row = m0 + wr * 64 + a * 16 + l4 * 4 + j;
                const int col = n0 + wc * 64 + b * 16 + l15;
                out[(size_t)row * H_ + col] = acc[a][b][j];
            }
}

} // namespace

extern "C" void kernel_launch(void* const* d_in, const int* in_sizes, int n_in,
                              void* d_out, int out_size, void* d_ws, size_t ws_size,
                              hipStream_t stream) {
    const float* x   = (const float*)d_in[0];   // [T, H]
    const float* wgu = (const float*)d_in[1];   // [E, 2I, H]
    const float* wdn = (const float*)d_in[2];   // [E, H, I]
    const int* eidx  = (const int*)d_in[3];     // [1]
    float* out = (float*)d_out;                 // [T, H]

    // d_out (134.2 MB fp32) temporarily holds xb (67.1 MB) — dead before k_gemm2
    // overwrites it. ws: hidden | wgu_bf16 | wdn_bf16 = 69.2 MB.
    unsigned short* xb     = (unsigned short*)d_out;
    unsigned short* hidden = (unsigned short*)d_ws;
    unsigned short* wgub   = (unsigned short*)((char*)d_ws + 50331648);
    unsigned short* wdnb   = (unsigned short*)((char*)d_ws + 62914560);

    k_cvt<<<2048, 256, 0, stream>>>(x, eidx, 0L, xb, (T_ * H_) / 4);
    k_cvt<<<2048, 256, 0, stream>>>(wgu, eidx, (long)(2 * I_) * H_, wgub, (2 * I_ * H_) / 4);
    k_cvt<<<2048, 256, 0, stream>>>(wdn, eidx, (long)H_ * I_, wdnb, (H_ * I_) / 4);
    k_gemm1_swiglu<<<dim3((I_ / 128) * (T_ / 128)), 256, 0, stream>>>(xb, wgub, hidden);
    k_gemm2<<<dim3((H_ / 128) * (T_ / 128)), 256, 0, stream>>>(hidden, wdnb, out);
}